// Round 7
// baseline (1031.622 us; speedup 1.0000x reference)
//
#include <hip/hip_runtime.h>
#include <hip/hip_bf16.h>

#define NN 50000
#define NE 800000
#define CI 64
#define CO 128
#define SCANB 49        // ceil(NN/1024)
#define PN (NN * 32)    // elements per 32-channel chunk plane (3.2 MB bf16)
#define NGRP 3125       // 16-node groups per chunk (3125*16 = 50000)

typedef __attribute__((ext_vector_type(8))) short bf16x8;
typedef __attribute__((ext_vector_type(4))) float f32x4;

__device__ __forceinline__ unsigned short f2bf(float f) {
  unsigned int u = __float_as_uint(f);
  u += 0x7fffu + ((u >> 16) & 1u);   // RNE; inputs are finite
  return (unsigned short)(u >> 16);
}
__device__ __forceinline__ float bf2f_lo(unsigned int p) { return __uint_as_float(p << 16); }
__device__ __forceinline__ float bf2f_hi(unsigned int p) { return __uint_as_float(p & 0xffff0000u); }
__device__ __forceinline__ unsigned int pk2(float lo, float hi) {
  return ((unsigned int)f2bf(hi) << 16) | (unsigned int)f2bf(lo);
}
__device__ __forceinline__ int get_xcc() {
  int x;
  asm volatile("s_getreg_b32 %0, hwreg(HW_REG_XCC_ID)" : "=s"(x));
  return x & 7;
}

// ---------------- CSR build ----------------
__global__ __launch_bounds__(256) void k_count(const int* __restrict__ dst, int* __restrict__ deg) {
  int e0 = (blockIdx.x * blockDim.x + threadIdx.x) * 4;
  if (e0 + 3 < NE) {
    int4 d = *(const int4*)(dst + e0);
    atomicAdd(&deg[d.x], 1); atomicAdd(&deg[d.y], 1);
    atomicAdd(&deg[d.z], 1); atomicAdd(&deg[d.w], 1);
  } else {
    for (int e = e0; e < NE; ++e) atomicAdd(&deg[dst[e]], 1);
  }
}

__global__ __launch_bounds__(256) void k_scan1(const int* __restrict__ deg, int* __restrict__ bsum) {
  int i0 = blockIdx.x * 1024 + threadIdx.x * 4;
  int s = 0;
#pragma unroll
  for (int j = 0; j < 4; ++j) { int i = i0 + j; if (i < NN) s += deg[i]; }
#pragma unroll
  for (int off = 32; off; off >>= 1) s += __shfl_down(s, off);
  __shared__ int ws[4];
  if ((threadIdx.x & 63) == 0) ws[threadIdx.x >> 6] = s;
  __syncthreads();
  if (threadIdx.x == 0) bsum[blockIdx.x] = ws[0] + ws[1] + ws[2] + ws[3];
}

__global__ __launch_bounds__(64) void k_scan2(const int* __restrict__ bsum, int* __restrict__ boff) {
  int t = threadIdx.x;
  int v = (t < SCANB) ? bsum[t] : 0;
  int incl = v;
#pragma unroll
  for (int off = 1; off < 64; off <<= 1) {
    int o = __shfl_up(incl, off);
    if (t >= off) incl += o;
  }
  if (t < SCANB) boff[t] = incl - v;
}

__global__ __launch_bounds__(256) void k_scan3(const int* __restrict__ deg, const int* __restrict__ boff,
                                               int* __restrict__ row_off) {
  int b = blockIdx.x;
  int i0 = b * 1024 + threadIdx.x * 4;
  int v[4]; int tsum = 0;
#pragma unroll
  for (int j = 0; j < 4; ++j) { int i = i0 + j; v[j] = (i < NN) ? deg[i] : 0; tsum += v[j]; }
  int incl = tsum;
#pragma unroll
  for (int off = 1; off < 64; off <<= 1) {
    int o = __shfl_up(incl, off);
    if ((threadIdx.x & 63) >= (unsigned)off) incl += o;
  }
  __shared__ int ws[4];
  int w = threadIdx.x >> 6;
  if ((threadIdx.x & 63) == 63) ws[w] = incl;
  __syncthreads();
  int wbase = 0;
  for (int k = 0; k < 4; ++k) if (k < w) wbase += ws[k];
  int excl = boff[b] + wbase + incl - tsum;
#pragma unroll
  for (int j = 0; j < 4; ++j) { int i = i0 + j; if (i < NN) row_off[i] = excl; excl += v[j]; }
  if (b == 0 && threadIdx.x == 0) row_off[NN] = NE;
}

__global__ __launch_bounds__(256) void k_fill(const int* __restrict__ src, const int* __restrict__ dst,
                       const int* __restrict__ row_off, int* __restrict__ cursor,
                       int* __restrict__ ssrc) {
  int e0 = (blockIdx.x * blockDim.x + threadIdx.x) * 4;
  if (e0 + 3 < NE) {
    int4 d = *(const int4*)(dst + e0);
    int4 s = *(const int4*)(src + e0);
    int r0 = row_off[d.x], r1 = row_off[d.y], r2 = row_off[d.z], r3 = row_off[d.w];
    int p0 = atomicAdd(&cursor[d.x], 1);
    int p1 = atomicAdd(&cursor[d.y], 1);
    int p2 = atomicAdd(&cursor[d.z], 1);
    int p3 = atomicAdd(&cursor[d.w], 1);
    ssrc[r0 + p0] = s.x; ssrc[r1 + p1] = s.y;
    ssrc[r2 + p2] = s.z; ssrc[r3 + p3] = s.w;
  } else {
    for (int e = e0; e < NE; ++e) {
      int dd = dst[e];
      int pos = atomicAdd(&cursor[dd], 1);
      ssrc[row_off[dd] + pos] = src[e];
    }
  }
}

// ---------------- fused fp32->bf16 conversions: [u0 | x | weights] ----------------
// u0 is written CHUNK-MAJOR: plane p holds channels [p*32,(p+1)*32) of all nodes.
#define U4 1600000          // NN*CO/4
#define X4 800000           // NN*CI/4
__global__ __launch_bounds__(256) void k_cvt_all(const float* __restrict__ u0, const float* __restrict__ x,
    const float* __restrict__ w1, const float* __restrict__ m1,
    const float* __restrict__ m2, const float* __restrict__ m3,
    unsigned short* __restrict__ ubf, unsigned short* __restrict__ xb,
    unsigned short* __restrict__ wbf) {
  int i = blockIdx.x * blockDim.x + threadIdx.x;   // float4 index
  const float* sp; unsigned short* dp;
  if (i < U4) {
    int node = i >> 5, cq = i & 31;                // cq*4 = first channel
    int plane = cq >> 3, off = (cq & 7) * 4;
    sp = u0 + (size_t)i * 4;
    dp = ubf + (size_t)plane * PN + (size_t)node * 32 + off;
  }
  else if (i < U4 + X4) { int k = i - U4; sp = x + (size_t)k * 4; dp = xb + (size_t)k * 4; }
  else if (i < U4 + X4 + 14336) {
    int k = i - U4 - X4;
    dp = wbf + (size_t)k * 4;
    if (k < 2048) sp = w1 + (size_t)k * 4;
    else if (k < 6144) sp = m1 + (size_t)(k - 2048) * 4;
    else if (k < 10240) sp = m2 + (size_t)(k - 6144) * 4;
    else sp = m3 + (size_t)(k - 10240) * 4;
  } else return;
  float4 v = *(const float4*)sp;
  ushort2 lo = { f2bf(v.x), f2bf(v.y) };
  ushort2 hi = { f2bf(v.z), f2bf(v.w) };
  *(ushort2*)dp = lo;
  *(ushort2*)(dp + 2) = hi;
}

// ---------------- CSR gather, chunk-major, XCD-pinned via HW_REG_XCC_ID ----------------
// Work item = (chunk, 16-node group). Blocks on XCDs {2c,2c+1} claim chunk-c items
// from a 4-cursor atomic queue (steal-fallback => exact coverage regardless of the
// real block->XCD mapping). Each XCD then only touches one 3.2 MB chunk plane,
// fully resident in its 4 MB L2; chunk-major layout makes every 128-B line
// single-chunk (no wasted half-lines).
__global__ __launch_bounds__(256) void k_gather(const int* __restrict__ row_off,
    const int* __restrict__ ssrc, const unsigned short* __restrict__ ubf,
    unsigned short* __restrict__ agg, int* __restrict__ qcur) {
  __shared__ int s_item;
  if (threadIdx.x == 0) {
    int p = get_xcc() >> 1;            // preferred chunk for this XCD
    int item = -1;
    for (int k = 0; k < 4; ++k) {
      int cq = (p + k) & 3;
      int i = atomicAdd(&qcur[cq], 1);
      if (i < NGRP) { item = cq * NGRP + i; break; }
    }
    s_item = item;
  }
  __syncthreads();
  int item = s_item;
  if (item < 0) return;
  int chunk = item / NGRP;
  int grp = item - chunk * NGRP;

  int lane = threadIdx.x & 63;
  int node0 = grp * 16 + (threadIdx.x >> 6) * 4;
  int eg = lane >> 4, c = lane & 15;   // 4 edge groups x 16 dword lanes (64 B/row)
  const unsigned short* ub = ubf + (size_t)chunk * PN + c * 2;
  unsigned short* ag = agg + (size_t)chunk * PN + c * 2;
#pragma unroll
  for (int nn = 0; nn < 4; ++nn) {
    int node = node0 + nn;
    int beg = row_off[node], end = row_off[node + 1];
    float a0 = 0.f, a1 = 0.f;
    for (int base = beg; base < end; base += 64) {
      int e = base + lane;
      int sid = (e < end) ? ssrc[e] : 0;
      int cnt = min(64, end - base);
      int j = 0;
      for (; j + 16 <= cnt; j += 16) {   // 4 independent staged loads
        int s0 = __shfl(sid, j + eg);
        int s1 = __shfl(sid, j + 4 + eg);
        int s2 = __shfl(sid, j + 8 + eg);
        int s3 = __shfl(sid, j + 12 + eg);
        unsigned int r0 = *(const unsigned int*)(ub + (size_t)s0 * 32);
        unsigned int r1 = *(const unsigned int*)(ub + (size_t)s1 * 32);
        unsigned int r2 = *(const unsigned int*)(ub + (size_t)s2 * 32);
        unsigned int r3 = *(const unsigned int*)(ub + (size_t)s3 * 32);
        a0 += bf2f_lo(r0) + bf2f_lo(r1) + bf2f_lo(r2) + bf2f_lo(r3);
        a1 += bf2f_hi(r0) + bf2f_hi(r1) + bf2f_hi(r2) + bf2f_hi(r3);
      }
      for (; j + 4 <= cnt; j += 4) {
        int s = __shfl(sid, j + eg);
        unsigned int r = *(const unsigned int*)(ub + (size_t)s * 32);
        a0 += bf2f_lo(r); a1 += bf2f_hi(r);
      }
      int rem = cnt - j;
      if (rem) {
        int s = __shfl(sid, j + min(eg, rem - 1));
        if (eg < rem) {
          unsigned int r = *(const unsigned int*)(ub + (size_t)s * 32);
          a0 += bf2f_lo(r); a1 += bf2f_hi(r);
        }
      }
    }
    a0 += __shfl_xor(a0, 16); a0 += __shfl_xor(a0, 32);
    a1 += __shfl_xor(a1, 16); a1 += __shfl_xor(a1, 32);
    if (eg == 0)
      *(unsigned int*)(ag + (size_t)node * 32) = pk2(a0, a1);
  }
}

// ---------------- xw = bf16(x @ w1^T + b1), computed once (row-major) ----------------
__global__ __launch_bounds__(256) void k_xw(const unsigned short* __restrict__ A,
    const unsigned short* __restrict__ W, const float* __restrict__ bias,
    unsigned short* __restrict__ xwb) {
  int wave = threadIdx.x >> 6, lane = threadIdx.x & 63;
  int m = lane & 15, q = lane >> 4;
  int row0 = blockIdx.x * 64 + wave * 16;
  int arow = row0 + m; if (arow >= NN) arow = NN - 1;
  const unsigned short* Ar = A + (size_t)arow * CI;
  f32x4 acc[8];
#pragma unroll
  for (int tt = 0; tt < 8; ++tt) acc[tt] = (f32x4){0.f, 0.f, 0.f, 0.f};
#pragma unroll
  for (int ks = 0; ks < CI; ks += 32) {
    bf16x8 a = *(const bf16x8*)(Ar + ks + q * 8);
#pragma unroll
    for (int tt = 0; tt < 8; ++tt) {
      bf16x8 b = *(const bf16x8*)(W + (size_t)(tt * 16 + m) * CI + ks + q * 8);
      acc[tt] = __builtin_amdgcn_mfma_f32_16x16x32_bf16(a, b, acc[tt], 0, 0, 0);
    }
  }
#pragma unroll
  for (int tt = 0; tt < 8; ++tt) {
    int o = tt * 16 + m;
    float bv = bias[o];
#pragma unroll
    for (int r = 0; r < 4; ++r) {
      int node = row0 + q * 4 + r;
      if (node < NN) xwb[(size_t)node * CO + o] = f2bf(acc[tt][r] + bv);
    }
  }
}

// ---------------- fused 3-layer MLP + epilogue (agg/uout chunk-major) ----------------
__global__ __launch_bounds__(128) void k_mlp(const unsigned short* __restrict__ agg,
    const unsigned short* __restrict__ W1, const unsigned short* __restrict__ W2,
    const unsigned short* __restrict__ W3,
    const float* __restrict__ b1, const float* __restrict__ b2, const float* __restrict__ b3,
    const unsigned short* __restrict__ xwb, unsigned short* __restrict__ uout) {
  constexpr int SP = 136;                 // 272 B row stride, 16B-aligned
  __shared__ unsigned short lds[2 * 32 * SP];
  int wave = threadIdx.x >> 6, lane = threadIdx.x & 63;
  int m = lane & 15, q = lane >> 4;
  int row0 = blockIdx.x * 64 + wave * 32;
  unsigned short* L = lds + wave * 32 * SP;
  int ar0 = row0 + m;      if (ar0 >= NN) ar0 = NN - 1;
  int ar1 = row0 + 16 + m; if (ar1 >= NN) ar1 = NN - 1;

  f32x4 acc[2][8];
#pragma unroll
  for (int g = 0; g < 2; ++g)
#pragma unroll
    for (int t = 0; t < 8; ++t) acc[g][t] = (f32x4){0.f, 0.f, 0.f, 0.f};

  // ---- layer 1: A from chunk-major agg ----
#pragma unroll
  for (int ks = 0; ks < CO; ks += 32) {
    const unsigned short* Ap = agg + (size_t)(ks >> 5) * PN + q * 8;
    bf16x8 a0 = *(const bf16x8*)(Ap + (size_t)ar0 * 32);
    bf16x8 a1 = *(const bf16x8*)(Ap + (size_t)ar1 * 32);
#pragma unroll
    for (int t = 0; t < 8; ++t) {
      bf16x8 b = *(const bf16x8*)(W1 + (size_t)(t * 16 + m) * CO + ks + q * 8);
      acc[0][t] = __builtin_amdgcn_mfma_f32_16x16x32_bf16(a0, b, acc[0][t], 0, 0, 0);
      acc[1][t] = __builtin_amdgcn_mfma_f32_16x16x32_bf16(a1, b, acc[1][t], 0, 0, 0);
    }
  }
#pragma unroll
  for (int t = 0; t < 8; ++t) {
    float bv = b1[t * 16 + m];
#pragma unroll
    for (int g = 0; g < 2; ++g)
#pragma unroll
      for (int r = 0; r < 4; ++r)
        L[(g * 16 + q * 4 + r) * SP + t * 16 + m] = f2bf(fmaxf(acc[g][t][r] + bv, 0.f));
  }
  // ---- layer 2 ----
#pragma unroll
  for (int g = 0; g < 2; ++g)
#pragma unroll
    for (int t = 0; t < 8; ++t) acc[g][t] = (f32x4){0.f, 0.f, 0.f, 0.f};
#pragma unroll
  for (int ks = 0; ks < CO; ks += 32) {
    bf16x8 a0 = *(const bf16x8*)(L + m * SP + ks + q * 8);
    bf16x8 a1 = *(const bf16x8*)(L + (16 + m) * SP + ks + q * 8);
#pragma unroll
    for (int t = 0; t < 8; ++t) {
      bf16x8 b = *(const bf16x8*)(W2 + (size_t)(t * 16 + m) * CO + ks + q * 8);
      acc[0][t] = __builtin_amdgcn_mfma_f32_16x16x32_bf16(a0, b, acc[0][t], 0, 0, 0);
      acc[1][t] = __builtin_amdgcn_mfma_f32_16x16x32_bf16(a1, b, acc[1][t], 0, 0, 0);
    }
  }
#pragma unroll
  for (int t = 0; t < 8; ++t) {
    float bv = b2[t * 16 + m];
#pragma unroll
    for (int g = 0; g < 2; ++g)
#pragma unroll
      for (int r = 0; r < 4; ++r)
        L[(g * 16 + q * 4 + r) * SP + t * 16 + m] = f2bf(fmaxf(acc[g][t][r] + bv, 0.f));
  }
  // ---- layer 3 ----
#pragma unroll
  for (int g = 0; g < 2; ++g)
#pragma unroll
    for (int t = 0; t < 8; ++t) acc[g][t] = (f32x4){0.f, 0.f, 0.f, 0.f};
#pragma unroll
  for (int ks = 0; ks < CO; ks += 32) {
    bf16x8 a0 = *(const bf16x8*)(L + m * SP + ks + q * 8);
    bf16x8 a1 = *(const bf16x8*)(L + (16 + m) * SP + ks + q * 8);
#pragma unroll
    for (int t = 0; t < 8; ++t) {
      bf16x8 b = *(const bf16x8*)(W3 + (size_t)(t * 16 + m) * CO + ks + q * 8);
      acc[0][t] = __builtin_amdgcn_mfma_f32_16x16x32_bf16(a0, b, acc[0][t], 0, 0, 0);
      acc[1][t] = __builtin_amdgcn_mfma_f32_16x16x32_bf16(a1, b, acc[1][t], 0, 0, 0);
    }
  }
  // tanh -> LDS
#pragma unroll
  for (int t = 0; t < 8; ++t) {
    float bv = b3[t * 16 + m];
#pragma unroll
    for (int g = 0; g < 2; ++g)
#pragma unroll
      for (int r = 0; r < 4; ++r) {
        float v = acc[g][t][r] + bv;
        float e = __expf(2.f * v);
        v = 1.f - 2.f / (e + 1.f);        // tanh
        L[(g * 16 + q * 4 + r) * SP + t * 16 + m] = f2bf(v);
      }
  }
  // fused store: u = relu(xw + tanh); uout chunk-major, 16B packed
  int ln = lane >> 1, lc = lane & 1;
  int gnode = row0 + ln;
  if (gnode < NN) {
    const unsigned short* xr = xwb + (size_t)gnode * CO;
#pragma unroll
    for (int rnd = 0; rnd < 8; ++rnd) {
      int ch = (rnd * 2 + lc) * 8;
      uint4 h = *(const uint4*)(L + ln * SP + ch);
      uint4 xv = *(const uint4*)(xr + ch);
      uint4 o;
      o.x = pk2(fmaxf(bf2f_lo(h.x) + bf2f_lo(xv.x), 0.f), fmaxf(bf2f_hi(h.x) + bf2f_hi(xv.x), 0.f));
      o.y = pk2(fmaxf(bf2f_lo(h.y) + bf2f_lo(xv.y), 0.f), fmaxf(bf2f_hi(h.y) + bf2f_hi(xv.y), 0.f));
      o.z = pk2(fmaxf(bf2f_lo(h.z) + bf2f_lo(xv.z), 0.f), fmaxf(bf2f_hi(h.z) + bf2f_hi(xv.z), 0.f));
      o.w = pk2(fmaxf(bf2f_lo(h.w) + bf2f_lo(xv.w), 0.f), fmaxf(bf2f_hi(h.w) + bf2f_hi(xv.w), 0.f));
      *(uint4*)(uout + (size_t)(ch >> 5) * PN + (size_t)gnode * 32 + (ch & 31)) = o;
    }
  }
}

// ---------------- final readout (u chunk-major) ----------------
__global__ __launch_bounds__(256) void k_reduce(const unsigned short* __restrict__ u,
                                                float* __restrict__ g) {
  int ch2 = threadIdx.x & 63;
  int sub = threadIdx.x >> 6;
  const unsigned short* up = u + (size_t)(ch2 >> 4) * PN + (ch2 & 15) * 2;
  float a0 = 0.f, a1 = 0.f;
  for (int n = blockIdx.x * 4 + sub; n < NN; n += gridDim.x * 4) {
    unsigned int p = *(const unsigned int*)(up + (size_t)n * 32);
    a0 += bf2f_lo(p); a1 += bf2f_hi(p);
  }
  __shared__ float s0[256], s1[256];
  s0[threadIdx.x] = a0; s1[threadIdx.x] = a1;
  __syncthreads();
  if (sub == 0) {
    a0 = s0[ch2] + s0[64 + ch2] + s0[128 + ch2] + s0[192 + ch2];
    a1 = s1[ch2] + s1[64 + ch2] + s1[128 + ch2] + s1[192 + ch2];
    atomicAdd(&g[ch2 * 2], a0);
    atomicAdd(&g[ch2 * 2 + 1], a1);
  }
}

__global__ void k_final(const float* __restrict__ g, const float* __restrict__ w2,
                        const float* __restrict__ b2, float* __restrict__ outp) {
  __shared__ float sg[128];
  if (threadIdx.x < 128) sg[threadIdx.x] = g[threadIdx.x];
  __syncthreads();
  int j = threadIdx.x;
  if (j < 128) {
    float acc = b2[j];
    for (int c = 0; c < 128; ++c) acc += sg[c] * w2[j * 128 + c];
    outp[j] = acc;
  }
}

extern "C" void kernel_launch(void* const* d_in, const int* in_sizes, int n_in,
                              void* d_out, int out_size, void* d_ws, size_t ws_size,
                              hipStream_t stream) {
  (void)in_sizes; (void)n_in; (void)out_size; (void)ws_size;
  const float* x   = (const float*)d_in[0];
  const float* u0  = (const float*)d_in[1];
  const int*   ei  = (const int*)d_in[2];
  const float* w1W = (const float*)d_in[3];
  const float* w1b = (const float*)d_in[4];
  const float* m1W = (const float*)d_in[5];
  const float* m1b = (const float*)d_in[6];
  const float* m2W = (const float*)d_in[7];
  const float* m2b = (const float*)d_in[8];
  const float* m3W = (const float*)d_in[9];
  const float* m3b = (const float*)d_in[10];
  const float* w2W = (const float*)d_in[11];
  const float* w2b = (const float*)d_in[12];
  const int* esrc = ei;
  const int* edst = ei + NE;

  char* p = (char*)d_ws;
  auto carve = [&](size_t bytes) { char* r = p; p += (bytes + 255) & ~(size_t)255; return r; };
  unsigned short* xwb     = (unsigned short*)carve((size_t)NN * CO * 2);
  unsigned short* ubf     = (unsigned short*)carve((size_t)NN * CO * 2);  // 4 chunk planes
  unsigned short* agg     = (unsigned short*)carve((size_t)NN * CO * 2);  // 4 chunk planes
  unsigned short* xb      = (unsigned short*)carve((size_t)NN * CI * 2);
  unsigned short* wbf     = (unsigned short*)carve((size_t)57344 * 2);
  int*            row_off = (int*)carve((size_t)(NN + 1) * 4);
  int*            deg     = (int*)carve((size_t)NN * 4);
  int*            cursor  = (int*)carve((size_t)NN * 4);
  int*            ssrc    = (int*)carve((size_t)NE * 4);
  int*            bsum    = (int*)carve((size_t)SCANB * 4);
  int*            boff    = (int*)carve((size_t)SCANB * 4);
  float*          g       = (float*)carve(128 * 4);     // 512 B, 256-aligned
  int*            qcur    = (int*)carve(4 * 4 * 4);     // 4 cursors per iteration

  hipMemsetAsync(deg, 0, (size_t)NN * 4, stream);
  hipMemsetAsync(cursor, 0, (size_t)NN * 4, stream);
  hipMemsetAsync(g, 0, 128 * 4 + 256, stream);          // g + first qcur set... (g pad)
  hipMemsetAsync(qcur, 0, 4 * 4 * 4, stream);           // all 4 iterations' cursors

  k_count<<<(NE / 4 + 255) / 256, 256, 0, stream>>>(edst, deg);
  k_scan1<<<SCANB, 256, 0, stream>>>(deg, bsum);
  k_scan2<<<1, 64, 0, stream>>>(bsum, boff);
  k_scan3<<<SCANB, 256, 0, stream>>>(deg, boff, row_off);
  k_fill<<<(NE / 4 + 255) / 256, 256, 0, stream>>>(esrc, edst, row_off, cursor, ssrc);
  k_cvt_all<<<(U4 + X4 + 14336 + 255) / 256, 256, 0, stream>>>(u0, x, w1W, m1W, m2W, m3W,
                                                               ubf, xb, wbf);

  k_xw<<<(NN + 63) / 64, 256, 0, stream>>>(xb, wbf, w1b, xwb);

  const unsigned short* Wm1 = wbf + 8192;
  const unsigned short* Wm2 = wbf + 8192 + 16384;
  const unsigned short* Wm3 = wbf + 8192 + 2 * 16384;
  const int GM = (NN + 63) / 64;
  for (int it = 0; it < 4; ++it) {
    k_gather<<<4 * NGRP, 256, 0, stream>>>(row_off, ssrc, ubf, agg, qcur + it * 4);
    k_mlp<<<GM, 128, 0, stream>>>(agg, Wm1, Wm2, Wm3, m1b, m2b, m3b, xwb, ubf);
  }

  k_reduce<<<256, 256, 0, stream>>>(ubf, g);
  k_final<<<1, 128, 0, stream>>>(g, w2W, w2b, (float*)d_out);
}

// Round 8
// 597.614 us; speedup vs baseline: 1.7262x; 1.7262x over previous
//
#include <hip/hip_runtime.h>
#include <hip/hip_bf16.h>

#define NN 50000
#define NE 800000
#define CI 64
#define CO 128
#define SCANB 49        // ceil(NN/1024)
#define PN (NN * 32)    // elements per 32-channel chunk plane (3.2 MB bf16)
#define NGRP 3125       // 16-node groups per chunk (3125*16 = 50000)

typedef __attribute__((ext_vector_type(8))) short bf16x8;
typedef __attribute__((ext_vector_type(4))) float f32x4;

__device__ __forceinline__ unsigned short f2bf(float f) {
  unsigned int u = __float_as_uint(f);
  u += 0x7fffu + ((u >> 16) & 1u);   // RNE; inputs are finite
  return (unsigned short)(u >> 16);
}
__device__ __forceinline__ float bf2f_lo(unsigned int p) { return __uint_as_float(p << 16); }
__device__ __forceinline__ float bf2f_hi(unsigned int p) { return __uint_as_float(p & 0xffff0000u); }
__device__ __forceinline__ unsigned int pk2(float lo, float hi) {
  return ((unsigned int)f2bf(hi) << 16) | (unsigned int)f2bf(lo);
}

// ---------------- CSR build ----------------
__global__ __launch_bounds__(256) void k_count(const int* __restrict__ dst, int* __restrict__ deg) {
  int e0 = (blockIdx.x * blockDim.x + threadIdx.x) * 4;
  if (e0 + 3 < NE) {
    int4 d = *(const int4*)(dst + e0);
    atomicAdd(&deg[d.x], 1); atomicAdd(&deg[d.y], 1);
    atomicAdd(&deg[d.z], 1); atomicAdd(&deg[d.w], 1);
  } else {
    for (int e = e0; e < NE; ++e) atomicAdd(&deg[dst[e]], 1);
  }
}

__global__ __launch_bounds__(256) void k_scan1(const int* __restrict__ deg, int* __restrict__ bsum) {
  int i0 = blockIdx.x * 1024 + threadIdx.x * 4;
  int s = 0;
#pragma unroll
  for (int j = 0; j < 4; ++j) { int i = i0 + j; if (i < NN) s += deg[i]; }
#pragma unroll
  for (int off = 32; off; off >>= 1) s += __shfl_down(s, off);
  __shared__ int ws[4];
  if ((threadIdx.x & 63) == 0) ws[threadIdx.x >> 6] = s;
  __syncthreads();
  if (threadIdx.x == 0) bsum[blockIdx.x] = ws[0] + ws[1] + ws[2] + ws[3];
}

__global__ __launch_bounds__(64) void k_scan2(const int* __restrict__ bsum, int* __restrict__ boff) {
  int t = threadIdx.x;
  int v = (t < SCANB) ? bsum[t] : 0;
  int incl = v;
#pragma unroll
  for (int off = 1; off < 64; off <<= 1) {
    int o = __shfl_up(incl, off);
    if (t >= off) incl += o;
  }
  if (t < SCANB) boff[t] = incl - v;
}

__global__ __launch_bounds__(256) void k_scan3(const int* __restrict__ deg, const int* __restrict__ boff,
                                               int* __restrict__ row_off) {
  int b = blockIdx.x;
  int i0 = b * 1024 + threadIdx.x * 4;
  int v[4]; int tsum = 0;
#pragma unroll
  for (int j = 0; j < 4; ++j) { int i = i0 + j; v[j] = (i < NN) ? deg[i] : 0; tsum += v[j]; }
  int incl = tsum;
#pragma unroll
  for (int off = 1; off < 64; off <<= 1) {
    int o = __shfl_up(incl, off);
    if ((threadIdx.x & 63) >= (unsigned)off) incl += o;
  }
  __shared__ int ws[4];
  int w = threadIdx.x >> 6;
  if ((threadIdx.x & 63) == 63) ws[w] = incl;
  __syncthreads();
  int wbase = 0;
  for (int k = 0; k < 4; ++k) if (k < w) wbase += ws[k];
  int excl = boff[b] + wbase + incl - tsum;
#pragma unroll
  for (int j = 0; j < 4; ++j) { int i = i0 + j; if (i < NN) row_off[i] = excl; excl += v[j]; }
  if (b == 0 && threadIdx.x == 0) row_off[NN] = NE;
}

__global__ __launch_bounds__(256) void k_fill(const int* __restrict__ src, const int* __restrict__ dst,
                       const int* __restrict__ row_off, int* __restrict__ cursor,
                       int* __restrict__ ssrc) {
  int e0 = (blockIdx.x * blockDim.x + threadIdx.x) * 4;
  if (e0 + 3 < NE) {
    int4 d = *(const int4*)(dst + e0);
    int4 s = *(const int4*)(src + e0);
    int r0 = row_off[d.x], r1 = row_off[d.y], r2 = row_off[d.z], r3 = row_off[d.w];
    int p0 = atomicAdd(&cursor[d.x], 1);
    int p1 = atomicAdd(&cursor[d.y], 1);
    int p2 = atomicAdd(&cursor[d.z], 1);
    int p3 = atomicAdd(&cursor[d.w], 1);
    ssrc[r0 + p0] = s.x; ssrc[r1 + p1] = s.y;
    ssrc[r2 + p2] = s.z; ssrc[r3 + p3] = s.w;
  } else {
    for (int e = e0; e < NE; ++e) {
      int dd = dst[e];
      int pos = atomicAdd(&cursor[dd], 1);
      ssrc[row_off[dd] + pos] = src[e];
    }
  }
}

// ---------------- fused fp32->bf16 conversions: [u0 | x | weights] ----------------
// u0 is written CHUNK-MAJOR: plane p holds channels [p*32,(p+1)*32) of all nodes.
#define U4 1600000          // NN*CO/4
#define X4 800000           // NN*CI/4
__global__ __launch_bounds__(256) void k_cvt_all(const float* __restrict__ u0, const float* __restrict__ x,
    const float* __restrict__ w1, const float* __restrict__ m1,
    const float* __restrict__ m2, const float* __restrict__ m3,
    unsigned short* __restrict__ ubf, unsigned short* __restrict__ xb,
    unsigned short* __restrict__ wbf) {
  int i = blockIdx.x * blockDim.x + threadIdx.x;   // float4 index
  const float* sp; unsigned short* dp;
  if (i < U4) {
    int node = i >> 5, cq = i & 31;                // cq*4 = first channel
    int plane = cq >> 3, off = (cq & 7) * 4;
    sp = u0 + (size_t)i * 4;
    dp = ubf + (size_t)plane * PN + (size_t)node * 32 + off;
  }
  else if (i < U4 + X4) { int k = i - U4; sp = x + (size_t)k * 4; dp = xb + (size_t)k * 4; }
  else if (i < U4 + X4 + 14336) {
    int k = i - U4 - X4;
    dp = wbf + (size_t)k * 4;
    if (k < 2048) sp = w1 + (size_t)k * 4;
    else if (k < 6144) sp = m1 + (size_t)(k - 2048) * 4;
    else if (k < 10240) sp = m2 + (size_t)(k - 6144) * 4;
    else sp = m3 + (size_t)(k - 10240) * 4;
  } else return;
  float4 v = *(const float4*)sp;
  ushort2 lo = { f2bf(v.x), f2bf(v.y) };
  ushort2 hi = { f2bf(v.z), f2bf(v.w) };
  *(ushort2*)dp = lo;
  *(ushort2*)(dp + 2) = hi;
}

// ---------------- CSR gather, chunk-major planes, static XCD-aligned chunks ----------------
// chunk = (blockIdx&7)>>1: under round-robin block->XCD dispatch, XCD pair {2c,2c+1}
// only touches plane c (3.2 MB, resident in that XCD's 4 MB L2). Chunk-major layout
// makes every 128-B line single-chunk (two adjacent source rows per line).
// Correct under ANY mapping (coverage is static); pinning only affects speed.
__global__ __launch_bounds__(256) void k_gather(const int* __restrict__ row_off,
    const int* __restrict__ ssrc, const unsigned short* __restrict__ ubf,
    unsigned short* __restrict__ agg) {
  int b = blockIdx.x;
  int chunk = (b & 7) >> 1;
  int grp = (b >> 3) * 2 + (b & 1);
  if (grp >= NGRP) return;

  int lane = threadIdx.x & 63;
  int node0 = grp * 16 + (threadIdx.x >> 6) * 4;
  int eg = lane >> 4, c = lane & 15;   // 4 edge groups x 16 dword lanes (64 B/row)
  const unsigned short* ub = ubf + (size_t)chunk * PN + c * 2;
  unsigned short* ag = agg + (size_t)chunk * PN + c * 2;
#pragma unroll
  for (int nn = 0; nn < 4; ++nn) {
    int node = node0 + nn;
    int beg = row_off[node], end = row_off[node + 1];
    float a0 = 0.f, a1 = 0.f;
    for (int base = beg; base < end; base += 64) {
      int e = base + lane;
      int sid = (e < end) ? ssrc[e] : 0;
      int cnt = min(64, end - base);
      int j = 0;
      for (; j + 16 <= cnt; j += 16) {   // 4 independent staged loads
        int s0 = __shfl(sid, j + eg);
        int s1 = __shfl(sid, j + 4 + eg);
        int s2 = __shfl(sid, j + 8 + eg);
        int s3 = __shfl(sid, j + 12 + eg);
        unsigned int r0 = *(const unsigned int*)(ub + (size_t)s0 * 32);
        unsigned int r1 = *(const unsigned int*)(ub + (size_t)s1 * 32);
        unsigned int r2 = *(const unsigned int*)(ub + (size_t)s2 * 32);
        unsigned int r3 = *(const unsigned int*)(ub + (size_t)s3 * 32);
        a0 += bf2f_lo(r0) + bf2f_lo(r1) + bf2f_lo(r2) + bf2f_lo(r3);
        a1 += bf2f_hi(r0) + bf2f_hi(r1) + bf2f_hi(r2) + bf2f_hi(r3);
      }
      for (; j + 4 <= cnt; j += 4) {
        int s = __shfl(sid, j + eg);
        unsigned int r = *(const unsigned int*)(ub + (size_t)s * 32);
        a0 += bf2f_lo(r); a1 += bf2f_hi(r);
      }
      int rem = cnt - j;
      if (rem) {
        int s = __shfl(sid, j + min(eg, rem - 1));
        if (eg < rem) {
          unsigned int r = *(const unsigned int*)(ub + (size_t)s * 32);
          a0 += bf2f_lo(r); a1 += bf2f_hi(r);
        }
      }
    }
    a0 += __shfl_xor(a0, 16); a0 += __shfl_xor(a0, 32);
    a1 += __shfl_xor(a1, 16); a1 += __shfl_xor(a1, 32);
    if (eg == 0)
      *(unsigned int*)(ag + (size_t)node * 32) = pk2(a0, a1);
  }
}

// ---------------- xw = bf16(x @ w1^T + b1), computed once (row-major) ----------------
__global__ __launch_bounds__(256) void k_xw(const unsigned short* __restrict__ A,
    const unsigned short* __restrict__ W, const float* __restrict__ bias,
    unsigned short* __restrict__ xwb) {
  int wave = threadIdx.x >> 6, lane = threadIdx.x & 63;
  int m = lane & 15, q = lane >> 4;
  int row0 = blockIdx.x * 64 + wave * 16;
  int arow = row0 + m; if (arow >= NN) arow = NN - 1;
  const unsigned short* Ar = A + (size_t)arow * CI;
  f32x4 acc[8];
#pragma unroll
  for (int tt = 0; tt < 8; ++tt) acc[tt] = (f32x4){0.f, 0.f, 0.f, 0.f};
#pragma unroll
  for (int ks = 0; ks < CI; ks += 32) {
    bf16x8 a = *(const bf16x8*)(Ar + ks + q * 8);
#pragma unroll
    for (int tt = 0; tt < 8; ++tt) {
      bf16x8 b = *(const bf16x8*)(W + (size_t)(tt * 16 + m) * CI + ks + q * 8);
      acc[tt] = __builtin_amdgcn_mfma_f32_16x16x32_bf16(a, b, acc[tt], 0, 0, 0);
    }
  }
#pragma unroll
  for (int tt = 0; tt < 8; ++tt) {
    int o = tt * 16 + m;
    float bv = bias[o];
#pragma unroll
    for (int r = 0; r < 4; ++r) {
      int node = row0 + q * 4 + r;
      if (node < NN) xwb[(size_t)node * CO + o] = f2bf(acc[tt][r] + bv);
    }
  }
}

// ---------------- fused 3-layer MLP + epilogue (agg/uout chunk-major) ----------------
__global__ __launch_bounds__(128) void k_mlp(const unsigned short* __restrict__ agg,
    const unsigned short* __restrict__ W1, const unsigned short* __restrict__ W2,
    const unsigned short* __restrict__ W3,
    const float* __restrict__ b1, const float* __restrict__ b2, const float* __restrict__ b3,
    const unsigned short* __restrict__ xwb, unsigned short* __restrict__ uout) {
  constexpr int SP = 136;                 // 272 B row stride, 16B-aligned
  __shared__ unsigned short lds[2 * 32 * SP];
  int wave = threadIdx.x >> 6, lane = threadIdx.x & 63;
  int m = lane & 15, q = lane >> 4;
  int row0 = blockIdx.x * 64 + wave * 32;
  unsigned short* L = lds + wave * 32 * SP;
  int ar0 = row0 + m;      if (ar0 >= NN) ar0 = NN - 1;
  int ar1 = row0 + 16 + m; if (ar1 >= NN) ar1 = NN - 1;

  f32x4 acc[2][8];
#pragma unroll
  for (int g = 0; g < 2; ++g)
#pragma unroll
    for (int t = 0; t < 8; ++t) acc[g][t] = (f32x4){0.f, 0.f, 0.f, 0.f};

  // ---- layer 1: A from chunk-major agg ----
#pragma unroll
  for (int ks = 0; ks < CO; ks += 32) {
    const unsigned short* Ap = agg + (size_t)(ks >> 5) * PN + q * 8;
    bf16x8 a0 = *(const bf16x8*)(Ap + (size_t)ar0 * 32);
    bf16x8 a1 = *(const bf16x8*)(Ap + (size_t)ar1 * 32);
#pragma unroll
    for (int t = 0; t < 8; ++t) {
      bf16x8 b = *(const bf16x8*)(W1 + (size_t)(t * 16 + m) * CO + ks + q * 8);
      acc[0][t] = __builtin_amdgcn_mfma_f32_16x16x32_bf16(a0, b, acc[0][t], 0, 0, 0);
      acc[1][t] = __builtin_amdgcn_mfma_f32_16x16x32_bf16(a1, b, acc[1][t], 0, 0, 0);
    }
  }
#pragma unroll
  for (int t = 0; t < 8; ++t) {
    float bv = b1[t * 16 + m];
#pragma unroll
    for (int g = 0; g < 2; ++g)
#pragma unroll
      for (int r = 0; r < 4; ++r)
        L[(g * 16 + q * 4 + r) * SP + t * 16 + m] = f2bf(fmaxf(acc[g][t][r] + bv, 0.f));
  }
  // ---- layer 2 ----
#pragma unroll
  for (int g = 0; g < 2; ++g)
#pragma unroll
    for (int t = 0; t < 8; ++t) acc[g][t] = (f32x4){0.f, 0.f, 0.f, 0.f};
#pragma unroll
  for (int ks = 0; ks < CO; ks += 32) {
    bf16x8 a0 = *(const bf16x8*)(L + m * SP + ks + q * 8);
    bf16x8 a1 = *(const bf16x8*)(L + (16 + m) * SP + ks + q * 8);
#pragma unroll
    for (int t = 0; t < 8; ++t) {
      bf16x8 b = *(const bf16x8*)(W2 + (size_t)(t * 16 + m) * CO + ks + q * 8);
      acc[0][t] = __builtin_amdgcn_mfma_f32_16x16x32_bf16(a0, b, acc[0][t], 0, 0, 0);
      acc[1][t] = __builtin_amdgcn_mfma_f32_16x16x32_bf16(a1, b, acc[1][t], 0, 0, 0);
    }
  }
#pragma unroll
  for (int t = 0; t < 8; ++t) {
    float bv = b2[t * 16 + m];
#pragma unroll
    for (int g = 0; g < 2; ++g)
#pragma unroll
      for (int r = 0; r < 4; ++r)
        L[(g * 16 + q * 4 + r) * SP + t * 16 + m] = f2bf(fmaxf(acc[g][t][r] + bv, 0.f));
  }
  // ---- layer 3 ----
#pragma unroll
  for (int g = 0; g < 2; ++g)
#pragma unroll
    for (int t = 0; t < 8; ++t) acc[g][t] = (f32x4){0.f, 0.f, 0.f, 0.f};
#pragma unroll
  for (int ks = 0; ks < CO; ks += 32) {
    bf16x8 a0 = *(const bf16x8*)(L + m * SP + ks + q * 8);
    bf16x8 a1 = *(const bf16x8*)(L + (16 + m) * SP + ks + q * 8);
#pragma unroll
    for (int t = 0; t < 8; ++t) {
      bf16x8 b = *(const bf16x8*)(W3 + (size_t)(t * 16 + m) * CO + ks + q * 8);
      acc[0][t] = __builtin_amdgcn_mfma_f32_16x16x32_bf16(a0, b, acc[0][t], 0, 0, 0);
      acc[1][t] = __builtin_amdgcn_mfma_f32_16x16x32_bf16(a1, b, acc[1][t], 0, 0, 0);
    }
  }
  // tanh -> LDS
#pragma unroll
  for (int t = 0; t < 8; ++t) {
    float bv = b3[t * 16 + m];
#pragma unroll
    for (int g = 0; g < 2; ++g)
#pragma unroll
      for (int r = 0; r < 4; ++r) {
        float v = acc[g][t][r] + bv;
        float e = __expf(2.f * v);
        v = 1.f - 2.f / (e + 1.f);        // tanh
        L[(g * 16 + q * 4 + r) * SP + t * 16 + m] = f2bf(v);
      }
  }
  // fused store: u = relu(xw + tanh); uout chunk-major, 16B packed
  int ln = lane >> 1, lc = lane & 1;
  int gnode = row0 + ln;
  if (gnode < NN) {
    const unsigned short* xr = xwb + (size_t)gnode * CO;
#pragma unroll
    for (int rnd = 0; rnd < 8; ++rnd) {
      int ch = (rnd * 2 + lc) * 8;
      uint4 h = *(const uint4*)(L + ln * SP + ch);
      uint4 xv = *(const uint4*)(xr + ch);
      uint4 o;
      o.x = pk2(fmaxf(bf2f_lo(h.x) + bf2f_lo(xv.x), 0.f), fmaxf(bf2f_hi(h.x) + bf2f_hi(xv.x), 0.f));
      o.y = pk2(fmaxf(bf2f_lo(h.y) + bf2f_lo(xv.y), 0.f), fmaxf(bf2f_hi(h.y) + bf2f_hi(xv.y), 0.f));
      o.z = pk2(fmaxf(bf2f_lo(h.z) + bf2f_lo(xv.z), 0.f), fmaxf(bf2f_hi(h.z) + bf2f_hi(xv.z), 0.f));
      o.w = pk2(fmaxf(bf2f_lo(h.w) + bf2f_lo(xv.w), 0.f), fmaxf(bf2f_hi(h.w) + bf2f_hi(xv.w), 0.f));
      *(uint4*)(uout + (size_t)(ch >> 5) * PN + (size_t)gnode * 32 + (ch & 31)) = o;
    }
  }
}

// ---------------- final readout (u chunk-major) ----------------
__global__ __launch_bounds__(256) void k_reduce(const unsigned short* __restrict__ u,
                                                float* __restrict__ g) {
  int ch2 = threadIdx.x & 63;
  int sub = threadIdx.x >> 6;
  const unsigned short* up = u + (size_t)(ch2 >> 4) * PN + (ch2 & 15) * 2;
  float a0 = 0.f, a1 = 0.f;
  for (int n = blockIdx.x * 4 + sub; n < NN; n += gridDim.x * 4) {
    unsigned int p = *(const unsigned int*)(up + (size_t)n * 32);
    a0 += bf2f_lo(p); a1 += bf2f_hi(p);
  }
  __shared__ float s0[256], s1[256];
  s0[threadIdx.x] = a0; s1[threadIdx.x] = a1;
  __syncthreads();
  if (sub == 0) {
    a0 = s0[ch2] + s0[64 + ch2] + s0[128 + ch2] + s0[192 + ch2];
    a1 = s1[ch2] + s1[64 + ch2] + s1[128 + ch2] + s1[192 + ch2];
    atomicAdd(&g[ch2 * 2], a0);
    atomicAdd(&g[ch2 * 2 + 1], a1);
  }
}

__global__ void k_final(const float* __restrict__ g, const float* __restrict__ w2,
                        const float* __restrict__ b2, float* __restrict__ outp) {
  __shared__ float sg[128];
  if (threadIdx.x < 128) sg[threadIdx.x] = g[threadIdx.x];
  __syncthreads();
  int j = threadIdx.x;
  if (j < 128) {
    float acc = b2[j];
    for (int c = 0; c < 128; ++c) acc += sg[c] * w2[j * 128 + c];
    outp[j] = acc;
  }
}

extern "C" void kernel_launch(void* const* d_in, const int* in_sizes, int n_in,
                              void* d_out, int out_size, void* d_ws, size_t ws_size,
                              hipStream_t stream) {
  (void)in_sizes; (void)n_in; (void)out_size; (void)ws_size;
  const float* x   = (const float*)d_in[0];
  const float* u0  = (const float*)d_in[1];
  const int*   ei  = (const int*)d_in[2];
  const float* w1W = (const float*)d_in[3];
  const float* w1b = (const float*)d_in[4];
  const float* m1W = (const float*)d_in[5];
  const float* m1b = (const float*)d_in[6];
  const float* m2W = (const float*)d_in[7];
  const float* m2b = (const float*)d_in[8];
  const float* m3W = (const float*)d_in[9];
  const float* m3b = (const float*)d_in[10];
  const float* w2W = (const float*)d_in[11];
  const float* w2b = (const float*)d_in[12];
  const int* esrc = ei;
  const int* edst = ei + NE;

  char* p = (char*)d_ws;
  auto carve = [&](size_t bytes) { char* r = p; p += (bytes + 255) & ~(size_t)255; return r; };
  unsigned short* xwb     = (unsigned short*)carve((size_t)NN * CO * 2);
  unsigned short* ubf     = (unsigned short*)carve((size_t)NN * CO * 2);  // 4 chunk planes
  unsigned short* agg     = (unsigned short*)carve((size_t)NN * CO * 2);  // 4 chunk planes
  unsigned short* xb      = (unsigned short*)carve((size_t)NN * CI * 2);
  unsigned short* wbf     = (unsigned short*)carve((size_t)57344 * 2);
  int*            row_off = (int*)carve((size_t)(NN + 1) * 4);
  int*            deg     = (int*)carve((size_t)NN * 4);
  int*            cursor  = (int*)carve((size_t)NN * 4);
  int*            ssrc    = (int*)carve((size_t)NE * 4);
  int*            bsum    = (int*)carve((size_t)SCANB * 4);
  int*            boff    = (int*)carve((size_t)SCANB * 4);
  float*          g       = (float*)carve(128 * 4);

  hipMemsetAsync(deg, 0, (size_t)NN * 4, stream);
  hipMemsetAsync(cursor, 0, (size_t)NN * 4, stream);
  hipMemsetAsync(g, 0, 128 * 4, stream);

  k_count<<<(NE / 4 + 255) / 256, 256, 0, stream>>>(edst, deg);
  k_scan1<<<SCANB, 256, 0, stream>>>(deg, bsum);
  k_scan2<<<1, 64, 0, stream>>>(bsum, boff);
  k_scan3<<<SCANB, 256, 0, stream>>>(deg, boff, row_off);
  k_fill<<<(NE / 4 + 255) / 256, 256, 0, stream>>>(esrc, edst, row_off, cursor, ssrc);
  k_cvt_all<<<(U4 + X4 + 14336 + 255) / 256, 256, 0, stream>>>(u0, x, w1W, m1W, m2W, m3W,
                                                               ubf, xb, wbf);

  k_xw<<<(NN + 63) / 64, 256, 0, stream>>>(xb, wbf, w1b, xwb);

  const unsigned short* Wm1 = wbf + 8192;
  const unsigned short* Wm2 = wbf + 8192 + 16384;
  const unsigned short* Wm3 = wbf + 8192 + 2 * 16384;
  const int GM = (NN + 63) / 64;
  const int GG = 8 * ((NGRP + 1) / 2);   // 8 residues x 1563 -> covers 4 chunks x 3125 groups
  for (int it = 0; it < 4; ++it) {
    k_gather<<<GG, 256, 0, stream>>>(row_off, ssrc, ubf, agg);
    k_mlp<<<GM, 128, 0, stream>>>(agg, Wm1, Wm2, Wm3, m1b, m2b, m3b, xwb, ubf);
  }

  k_reduce<<<256, 256, 0, stream>>>(ubf, g);
  k_final<<<1, 128, 0, stream>>>(g, w2W, w2b, (float*)d_out);
}

// Round 9
// 524.222 us; speedup vs baseline: 1.9679x; 1.1400x over previous
//
#include <hip/hip_runtime.h>
#include <hip/hip_bf16.h>

#define NN 50000
#define NE 800000
#define CI 64
#define CO 128
#define SCANB 49   // ceil(NN/1024)

typedef __attribute__((ext_vector_type(8))) short bf16x8;
typedef __attribute__((ext_vector_type(4))) float f32x4;

__device__ __forceinline__ unsigned short f2bf(float f) {
  unsigned int u = __float_as_uint(f);
  u += 0x7fffu + ((u >> 16) & 1u);   // RNE; inputs are finite
  return (unsigned short)(u >> 16);
}
__device__ __forceinline__ float bf2f_lo(unsigned int p) { return __uint_as_float(p << 16); }
__device__ __forceinline__ float bf2f_hi(unsigned int p) { return __uint_as_float(p & 0xffff0000u); }
__device__ __forceinline__ unsigned int pk2(float lo, float hi) {
  return ((unsigned int)f2bf(hi) << 16) | (unsigned int)f2bf(lo);
}

// ---------------- CSR build ----------------
__global__ __launch_bounds__(256) void k_count(const int* __restrict__ dst, int* __restrict__ deg) {
  int e0 = (blockIdx.x * blockDim.x + threadIdx.x) * 4;
  if (e0 + 3 < NE) {
    int4 d = *(const int4*)(dst + e0);
    atomicAdd(&deg[d.x], 1); atomicAdd(&deg[d.y], 1);
    atomicAdd(&deg[d.z], 1); atomicAdd(&deg[d.w], 1);
  } else {
    for (int e = e0; e < NE; ++e) atomicAdd(&deg[dst[e]], 1);
  }
}

__global__ __launch_bounds__(256) void k_scan1(const int* __restrict__ deg, int* __restrict__ bsum) {
  int i0 = blockIdx.x * 1024 + threadIdx.x * 4;
  int s = 0;
#pragma unroll
  for (int j = 0; j < 4; ++j) { int i = i0 + j; if (i < NN) s += deg[i]; }
#pragma unroll
  for (int off = 32; off; off >>= 1) s += __shfl_down(s, off);
  __shared__ int ws[4];
  if ((threadIdx.x & 63) == 0) ws[threadIdx.x >> 6] = s;
  __syncthreads();
  if (threadIdx.x == 0) bsum[blockIdx.x] = ws[0] + ws[1] + ws[2] + ws[3];
}

__global__ __launch_bounds__(64) void k_scan2(const int* __restrict__ bsum, int* __restrict__ boff) {
  int t = threadIdx.x;
  int v = (t < SCANB) ? bsum[t] : 0;
  int incl = v;
#pragma unroll
  for (int off = 1; off < 64; off <<= 1) {
    int o = __shfl_up(incl, off);
    if (t >= off) incl += o;
  }
  if (t < SCANB) boff[t] = incl - v;
}

__global__ __launch_bounds__(256) void k_scan3(const int* __restrict__ deg, const int* __restrict__ boff,
                                               int* __restrict__ row_off) {
  int b = blockIdx.x;
  int i0 = b * 1024 + threadIdx.x * 4;
  int v[4]; int tsum = 0;
#pragma unroll
  for (int j = 0; j < 4; ++j) { int i = i0 + j; v[j] = (i < NN) ? deg[i] : 0; tsum += v[j]; }
  int incl = tsum;
#pragma unroll
  for (int off = 1; off < 64; off <<= 1) {
    int o = __shfl_up(incl, off);
    if ((threadIdx.x & 63) >= (unsigned)off) incl += o;
  }
  __shared__ int ws[4];
  int w = threadIdx.x >> 6;
  if ((threadIdx.x & 63) == 63) ws[w] = incl;
  __syncthreads();
  int wbase = 0;
  for (int k = 0; k < 4; ++k) if (k < w) wbase += ws[k];
  int excl = boff[b] + wbase + incl - tsum;
#pragma unroll
  for (int j = 0; j < 4; ++j) { int i = i0 + j; if (i < NN) row_off[i] = excl; excl += v[j]; }
  if (b == 0 && threadIdx.x == 0) row_off[NN] = NE;
}

__global__ __launch_bounds__(256) void k_fill(const int* __restrict__ src, const int* __restrict__ dst,
                       const int* __restrict__ row_off, int* __restrict__ cursor,
                       int* __restrict__ ssrc) {
  int e0 = (blockIdx.x * blockDim.x + threadIdx.x) * 4;
  if (e0 + 3 < NE) {
    int4 d = *(const int4*)(dst + e0);
    int4 s = *(const int4*)(src + e0);
    int r0 = row_off[d.x], r1 = row_off[d.y], r2 = row_off[d.z], r3 = row_off[d.w];
    int p0 = atomicAdd(&cursor[d.x], 1);
    int p1 = atomicAdd(&cursor[d.y], 1);
    int p2 = atomicAdd(&cursor[d.z], 1);
    int p3 = atomicAdd(&cursor[d.w], 1);
    ssrc[r0 + p0] = s.x; ssrc[r1 + p1] = s.y;
    ssrc[r2 + p2] = s.z; ssrc[r3 + p3] = s.w;
  } else {
    for (int e = e0; e < NE; ++e) {
      int dd = dst[e];
      int pos = atomicAdd(&cursor[dd], 1);
      ssrc[row_off[dd] + pos] = src[e];
    }
  }
}

// ---------------- fused fp32->bf16 conversions: [u0 | x | weights], row-major ----------------
#define U4 1600000          // NN*CO/4
#define X4 800000           // NN*CI/4
__global__ __launch_bounds__(256) void k_cvt_all(const float* __restrict__ u0, const float* __restrict__ x,
    const float* __restrict__ w1, const float* __restrict__ m1,
    const float* __restrict__ m2, const float* __restrict__ m3,
    unsigned short* __restrict__ ubf, unsigned short* __restrict__ xb,
    unsigned short* __restrict__ wbf) {
  int i = blockIdx.x * blockDim.x + threadIdx.x;   // float4 index
  const float* sp; unsigned short* dp;
  if (i < U4) { sp = u0 + (size_t)i * 4; dp = ubf + (size_t)i * 4; }
  else if (i < U4 + X4) { int k = i - U4; sp = x + (size_t)k * 4; dp = xb + (size_t)k * 4; }
  else if (i < U4 + X4 + 14336) {
    int k = i - U4 - X4;
    dp = wbf + (size_t)k * 4;
    if (k < 2048) sp = w1 + (size_t)k * 4;
    else if (k < 6144) sp = m1 + (size_t)(k - 2048) * 4;
    else if (k < 10240) sp = m2 + (size_t)(k - 6144) * 4;
    else sp = m3 + (size_t)(k - 10240) * 4;
  } else return;
  float4 v = *(const float4*)sp;
  ushort2 lo = { f2bf(v.x), f2bf(v.y) };
  ushort2 hi = { f2bf(v.z), f2bf(v.w) };
  *(ushort2*)dp = lo;
  *(ushort2*)(dp + 2) = hi;
}

// ---------------- CSR gather (segment_sum): lane-owns-channels dataflow ----------------
// Lane c owns channels (2c,2c+1) in f32 registers. A source-row read is 64 lanes x
// 1 dword = 256 B fully coalesced (ONE segment). Edge indices are wave-uniform
// scalar reads (readfirstlane'd node -> scalar row_off/ssrc) -> SMEM pipe, zero DS.
// No cross-lane reduction at all. 4 nodes/wave, 4-edge staged batches.
__global__ __launch_bounds__(256) void k_gather(const int* __restrict__ row_off,
    const int* __restrict__ ssrc, const unsigned short* __restrict__ ubf,
    unsigned short* __restrict__ agg) {
  int wave = threadIdx.x >> 6, lane = threadIdx.x & 63;
  int node0 = blockIdx.x * 16 + wave * 4;          // NN = 3125*16 exactly
  const unsigned short* ub = ubf + lane * 2;
#pragma unroll
  for (int k = 0; k < 4; ++k) {
    int node = __builtin_amdgcn_readfirstlane(node0 + k);
    int beg = row_off[node], end = row_off[node + 1];   // uniform -> scalar loads
    float a0 = 0.f, a1 = 0.f;
    int j = beg;
    for (; j + 4 <= end; j += 4) {
      int s0 = ssrc[j], s1 = ssrc[j + 1], s2 = ssrc[j + 2], s3 = ssrc[j + 3];
      unsigned int d0 = *(const unsigned int*)(ub + (size_t)s0 * CO);
      unsigned int d1 = *(const unsigned int*)(ub + (size_t)s1 * CO);
      unsigned int d2 = *(const unsigned int*)(ub + (size_t)s2 * CO);
      unsigned int d3 = *(const unsigned int*)(ub + (size_t)s3 * CO);
      a0 += bf2f_lo(d0) + bf2f_lo(d1) + bf2f_lo(d2) + bf2f_lo(d3);
      a1 += bf2f_hi(d0) + bf2f_hi(d1) + bf2f_hi(d2) + bf2f_hi(d3);
    }
    for (; j < end; ++j) {
      int s = ssrc[j];
      unsigned int d = *(const unsigned int*)(ub + (size_t)s * CO);
      a0 += bf2f_lo(d); a1 += bf2f_hi(d);
    }
    *(unsigned int*)(agg + (size_t)node * CO + lane * 2) = pk2(a0, a1);  // 256 B coalesced
  }
}

// ---------------- xw = bf16(x @ w1^T + b1), computed once ----------------
__global__ __launch_bounds__(256) void k_xw(const unsigned short* __restrict__ A,
    const unsigned short* __restrict__ W, const float* __restrict__ bias,
    unsigned short* __restrict__ xwb) {
  int wave = threadIdx.x >> 6, lane = threadIdx.x & 63;
  int m = lane & 15, q = lane >> 4;
  int row0 = blockIdx.x * 64 + wave * 16;
  int arow = row0 + m; if (arow >= NN) arow = NN - 1;
  const unsigned short* Ar = A + (size_t)arow * CI;
  f32x4 acc[8];
#pragma unroll
  for (int tt = 0; tt < 8; ++tt) acc[tt] = (f32x4){0.f, 0.f, 0.f, 0.f};
#pragma unroll
  for (int ks = 0; ks < CI; ks += 32) {
    bf16x8 a = *(const bf16x8*)(Ar + ks + q * 8);
#pragma unroll
    for (int tt = 0; tt < 8; ++tt) {
      bf16x8 b = *(const bf16x8*)(W + (size_t)(tt * 16 + m) * CI + ks + q * 8);
      acc[tt] = __builtin_amdgcn_mfma_f32_16x16x32_bf16(a, b, acc[tt], 0, 0, 0);
    }
  }
#pragma unroll
  for (int tt = 0; tt < 8; ++tt) {
    int o = tt * 16 + m;
    float bv = bias[o];
#pragma unroll
    for (int r = 0; r < 4; ++r) {
      int node = row0 + q * 4 + r;
      if (node < NN) xwb[(size_t)node * CO + o] = f2bf(acc[tt][r] + bv);
    }
  }
}

// ---------------- fused 3-layer MLP + epilogue (row-major, r4-verified) ----------------
__global__ __launch_bounds__(128) void k_mlp(const unsigned short* __restrict__ agg,
    const unsigned short* __restrict__ W1, const unsigned short* __restrict__ W2,
    const unsigned short* __restrict__ W3,
    const float* __restrict__ b1, const float* __restrict__ b2, const float* __restrict__ b3,
    const unsigned short* __restrict__ xwb, unsigned short* __restrict__ uout) {
  constexpr int SP = 136;                 // 272 B row stride, 16B-aligned
  __shared__ unsigned short lds[2 * 32 * SP];
  int wave = threadIdx.x >> 6, lane = threadIdx.x & 63;
  int m = lane & 15, q = lane >> 4;
  int row0 = blockIdx.x * 64 + wave * 32;
  unsigned short* L = lds + wave * 32 * SP;
  int ar0 = row0 + m;      if (ar0 >= NN) ar0 = NN - 1;
  int ar1 = row0 + 16 + m; if (ar1 >= NN) ar1 = NN - 1;
  const unsigned short* A0p = agg + (size_t)ar0 * CO;
  const unsigned short* A1p = agg + (size_t)ar1 * CO;

  f32x4 acc[2][8];
#pragma unroll
  for (int g = 0; g < 2; ++g)
#pragma unroll
    for (int t = 0; t < 8; ++t) acc[g][t] = (f32x4){0.f, 0.f, 0.f, 0.f};

  // ---- layer 1 ----
#pragma unroll
  for (int ks = 0; ks < CO; ks += 32) {
    bf16x8 a0 = *(const bf16x8*)(A0p + ks + q * 8);
    bf16x8 a1 = *(const bf16x8*)(A1p + ks + q * 8);
#pragma unroll
    for (int t = 0; t < 8; ++t) {
      bf16x8 b = *(const bf16x8*)(W1 + (size_t)(t * 16 + m) * CO + ks + q * 8);
      acc[0][t] = __builtin_amdgcn_mfma_f32_16x16x32_bf16(a0, b, acc[0][t], 0, 0, 0);
      acc[1][t] = __builtin_amdgcn_mfma_f32_16x16x32_bf16(a1, b, acc[1][t], 0, 0, 0);
    }
  }
#pragma unroll
  for (int t = 0; t < 8; ++t) {
    float bv = b1[t * 16 + m];
#pragma unroll
    for (int g = 0; g < 2; ++g)
#pragma unroll
      for (int r = 0; r < 4; ++r)
        L[(g * 16 + q * 4 + r) * SP + t * 16 + m] = f2bf(fmaxf(acc[g][t][r] + bv, 0.f));
  }
  // ---- layer 2 ----
#pragma unroll
  for (int g = 0; g < 2; ++g)
#pragma unroll
    for (int t = 0; t < 8; ++t) acc[g][t] = (f32x4){0.f, 0.f, 0.f, 0.f};
#pragma unroll
  for (int ks = 0; ks < CO; ks += 32) {
    bf16x8 a0 = *(const bf16x8*)(L + m * SP + ks + q * 8);
    bf16x8 a1 = *(const bf16x8*)(L + (16 + m) * SP + ks + q * 8);
#pragma unroll
    for (int t = 0; t < 8; ++t) {
      bf16x8 b = *(const bf16x8*)(W2 + (size_t)(t * 16 + m) * CO + ks + q * 8);
      acc[0][t] = __builtin_amdgcn_mfma_f32_16x16x32_bf16(a0, b, acc[0][t], 0, 0, 0);
      acc[1][t] = __builtin_amdgcn_mfma_f32_16x16x32_bf16(a1, b, acc[1][t], 0, 0, 0);
    }
  }
#pragma unroll
  for (int t = 0; t < 8; ++t) {
    float bv = b2[t * 16 + m];
#pragma unroll
    for (int g = 0; g < 2; ++g)
#pragma unroll
      for (int r = 0; r < 4; ++r)
        L[(g * 16 + q * 4 + r) * SP + t * 16 + m] = f2bf(fmaxf(acc[g][t][r] + bv, 0.f));
  }
  // ---- layer 3 ----
#pragma unroll
  for (int g = 0; g < 2; ++g)
#pragma unroll
    for (int t = 0; t < 8; ++t) acc[g][t] = (f32x4){0.f, 0.f, 0.f, 0.f};
#pragma unroll
  for (int ks = 0; ks < CO; ks += 32) {
    bf16x8 a0 = *(const bf16x8*)(L + m * SP + ks + q * 8);
    bf16x8 a1 = *(const bf16x8*)(L + (16 + m) * SP + ks + q * 8);
#pragma unroll
    for (int t = 0; t < 8; ++t) {
      bf16x8 b = *(const bf16x8*)(W3 + (size_t)(t * 16 + m) * CO + ks + q * 8);
      acc[0][t] = __builtin_amdgcn_mfma_f32_16x16x32_bf16(a0, b, acc[0][t], 0, 0, 0);
      acc[1][t] = __builtin_amdgcn_mfma_f32_16x16x32_bf16(a1, b, acc[1][t], 0, 0, 0);
    }
  }
  // tanh -> LDS
#pragma unroll
  for (int t = 0; t < 8; ++t) {
    float bv = b3[t * 16 + m];
#pragma unroll
    for (int g = 0; g < 2; ++g)
#pragma unroll
      for (int r = 0; r < 4; ++r) {
        float v = acc[g][t][r] + bv;
        float e = __expf(2.f * v);
        v = 1.f - 2.f / (e + 1.f);        // tanh
        L[(g * 16 + q * 4 + r) * SP + t * 16 + m] = f2bf(v);
      }
  }
  // fused store: u = relu(xw + tanh) with packed b128 traffic
  int ln = lane >> 1, lc = lane & 1;
  int gnode = row0 + ln;
  if (gnode < NN) {
    const unsigned short* xr = xwb + (size_t)gnode * CO;
    unsigned short* ur = uout + (size_t)gnode * CO;
#pragma unroll
    for (int rnd = 0; rnd < 8; ++rnd) {
      int ch = (rnd * 2 + lc) * 8;
      uint4 h = *(const uint4*)(L + ln * SP + ch);
      uint4 xv = *(const uint4*)(xr + ch);
      uint4 o;
      o.x = pk2(fmaxf(bf2f_lo(h.x) + bf2f_lo(xv.x), 0.f), fmaxf(bf2f_hi(h.x) + bf2f_hi(xv.x), 0.f));
      o.y = pk2(fmaxf(bf2f_lo(h.y) + bf2f_lo(xv.y), 0.f), fmaxf(bf2f_hi(h.y) + bf2f_hi(xv.y), 0.f));
      o.z = pk2(fmaxf(bf2f_lo(h.z) + bf2f_lo(xv.z), 0.f), fmaxf(bf2f_hi(h.z) + bf2f_hi(xv.z), 0.f));
      o.w = pk2(fmaxf(bf2f_lo(h.w) + bf2f_lo(xv.w), 0.f), fmaxf(bf2f_hi(h.w) + bf2f_hi(xv.w), 0.f));
      *(uint4*)(ur + ch) = o;
    }
  }
}

// ---------------- final readout ----------------
__global__ __launch_bounds__(256) void k_reduce(const unsigned short* __restrict__ u,
                                                float* __restrict__ g) {
  int ch2 = threadIdx.x & 63;
  int sub = threadIdx.x >> 6;
  float a0 = 0.f, a1 = 0.f;
  for (int n = blockIdx.x * 4 + sub; n < NN; n += gridDim.x * 4) {
    unsigned int p = *(const unsigned int*)(u + (size_t)n * CO + ch2 * 2);
    a0 += bf2f_lo(p); a1 += bf2f_hi(p);
  }
  __shared__ float s0[256], s1[256];
  s0[threadIdx.x] = a0; s1[threadIdx.x] = a1;
  __syncthreads();
  if (sub == 0) {
    a0 = s0[ch2] + s0[64 + ch2] + s0[128 + ch2] + s0[192 + ch2];
    a1 = s1[ch2] + s1[64 + ch2] + s1[128 + ch2] + s1[192 + ch2];
    atomicAdd(&g[ch2 * 2], a0);
    atomicAdd(&g[ch2 * 2 + 1], a1);
  }
}

__global__ void k_final(const float* __restrict__ g, const float* __restrict__ w2,
                        const float* __restrict__ b2, float* __restrict__ outp) {
  __shared__ float sg[128];
  if (threadIdx.x < 128) sg[threadIdx.x] = g[threadIdx.x];
  __syncthreads();
  int j = threadIdx.x;
  if (j < 128) {
    float acc = b2[j];
    for (int c = 0; c < 128; ++c) acc += sg[c] * w2[j * 128 + c];
    outp[j] = acc;
  }
}

extern "C" void kernel_launch(void* const* d_in, const int* in_sizes, int n_in,
                              void* d_out, int out_size, void* d_ws, size_t ws_size,
                              hipStream_t stream) {
  (void)in_sizes; (void)n_in; (void)out_size; (void)ws_size;
  const float* x   = (const float*)d_in[0];
  const float* u0  = (const float*)d_in[1];
  const int*   ei  = (const int*)d_in[2];
  const float* w1W = (const float*)d_in[3];
  const float* w1b = (const float*)d_in[4];
  const float* m1W = (const float*)d_in[5];
  const float* m1b = (const float*)d_in[6];
  const float* m2W = (const float*)d_in[7];
  const float* m2b = (const float*)d_in[8];
  const float* m3W = (const float*)d_in[9];
  const float* m3b = (const float*)d_in[10];
  const float* w2W = (const float*)d_in[11];
  const float* w2b = (const float*)d_in[12];
  const int* esrc = ei;
  const int* edst = ei + NE;

  char* p = (char*)d_ws;
  auto carve = [&](size_t bytes) { char* r = p; p += (bytes + 255) & ~(size_t)255; return r; };
  unsigned short* xwb     = (unsigned short*)carve((size_t)NN * CO * 2);
  unsigned short* ubf     = (unsigned short*)carve((size_t)NN * CO * 2);
  unsigned short* agg     = (unsigned short*)carve((size_t)NN * CO * 2);
  unsigned short* xb      = (unsigned short*)carve((size_t)NN * CI * 2);
  unsigned short* wbf     = (unsigned short*)carve((size_t)57344 * 2);
  int*            row_off = (int*)carve((size_t)(NN + 1) * 4);
  int*            deg     = (int*)carve((size_t)NN * 4);
  int*            cursor  = (int*)carve((size_t)NN * 4);
  int*            ssrc    = (int*)carve((size_t)NE * 4);
  int*            bsum    = (int*)carve((size_t)SCANB * 4);
  int*            boff    = (int*)carve((size_t)SCANB * 4);
  float*          g       = (float*)carve(128 * 4);

  hipMemsetAsync(deg, 0, (size_t)NN * 4, stream);
  hipMemsetAsync(cursor, 0, (size_t)NN * 4, stream);
  hipMemsetAsync(g, 0, 128 * 4, stream);

  k_count<<<(NE / 4 + 255) / 256, 256, 0, stream>>>(edst, deg);
  k_scan1<<<SCANB, 256, 0, stream>>>(deg, bsum);
  k_scan2<<<1, 64, 0, stream>>>(bsum, boff);
  k_scan3<<<SCANB, 256, 0, stream>>>(deg, boff, row_off);
  k_fill<<<(NE / 4 + 255) / 256, 256, 0, stream>>>(esrc, edst, row_off, cursor, ssrc);
  k_cvt_all<<<(U4 + X4 + 14336 + 255) / 256, 256, 0, stream>>>(u0, x, w1W, m1W, m2W, m3W,
                                                               ubf, xb, wbf);

  k_xw<<<(NN + 63) / 64, 256, 0, stream>>>(xb, wbf, w1b, xwb);

  const unsigned short* Wm1 = wbf + 8192;
  const unsigned short* Wm2 = wbf + 8192 + 16384;
  const unsigned short* Wm3 = wbf + 8192 + 2 * 16384;
  const int GM = (NN + 63) / 64;
  for (int it = 0; it < 4; ++it) {
    k_gather<<<NN / 16, 256, 0, stream>>>(row_off, ssrc, ubf, agg);
    k_mlp<<<GM, 128, 0, stream>>>(agg, Wm1, Wm2, Wm3, m1b, m2b, m3b, xwb, ubf);
  }

  k_reduce<<<256, 256, 0, stream>>>(ubf, g);
  k_final<<<1, 128, 0, stream>>>(g, w2W, w2b, (float*)d_out);
}